// Round 5
// baseline (1022.045 us; speedup 1.0000x reference)
//
#include <hip/hip_runtime.h>
#include <math.h>

// Model dims (fixed by the reference)
#define T_DIM 512
#define B_DIM 64
#define J_DIM 256
#define H_DIM 256
#define K_TAP 25
#define NL    3
#define M_DIM (T_DIM*B_DIM)   // 32768 rows = (t,b)
#define NBH   (B_DIM*H_DIM)   // 16384
#define STATB 128

// conv GEMM tiling: block = 128(M) x 64(N), 4 waves (2x2), wave tile 64x32
#define MB 128
#define NB 64
#define KS 32
#define NST (K_TAP*(J_DIM/KS))  // 200 K-steps

typedef __attribute__((ext_vector_type(8))) short bf16x8;
typedef __attribute__((ext_vector_type(4))) float f32x4;

__device__ __forceinline__ unsigned short f2bf(float f){      // RNE f32->bf16
  unsigned u = __float_as_uint(f);
  return (unsigned short)((u + 0x7FFFu + ((u>>16)&1u)) >> 16);
}
__device__ __forceinline__ float bf2f(unsigned short h){
  return __uint_as_float(((unsigned)h)<<16);
}
__device__ __forceinline__ void gl16(const void* g, void* l){ // async global->LDS, 16B/lane
  __builtin_amdgcn_global_load_lds((const __attribute__((address_space(1))) unsigned int*)g,
                                   (__attribute__((address_space(3))) unsigned int*)l, 16, 0, 0);
}

// ---------------------------------------------------------------------------
// 0) cast f32 binary input -> u8 spikes
// ---------------------------------------------------------------------------
__global__ void cast_u8_k(const float* __restrict__ x, unsigned char* __restrict__ s){
  const int i = blockIdx.x*256 + threadIdx.x;       // one float4 per thread
  const float4 v = *(const float4*)(x + (size_t)i*4);
  uchar4 o; o.x=(unsigned char)v.x; o.y=(unsigned char)v.y;
  o.z=(unsigned char)v.z; o.w=(unsigned char)v.w;
  *(uchar4*)(s + (size_t)i*4) = o;
}

// ---------------------------------------------------------------------------
// 1) DCLS gaussian kernel -> 3-way bf16 split (error <= 2^-24 |kd|),
//    layout [d][o][j], PRE-SWIZZLED in j: the 16B slot field (j bits 3..4)
//    is XORed with (o>>1)&3 so that a LINEAR global_load_lds lands the data
//    bank-conflict-free for the MFMA fragment reads (T2, rule 21).
// ---------------------------------------------------------------------------
__global__ void build_kern_k(const float* __restrict__ W, const float* __restrict__ P,
                             unsigned short* __restrict__ kdh, unsigned short* __restrict__ kdm,
                             unsigned short* __restrict__ kdl, int layer){
  const int o = blockIdx.x, j = threadIdx.x;
  const float w = W[(layer*H_DIM + o)*J_DIM + j];
  const float p = P[(layer*H_DIM + o)*J_DIM + j];
  const float c = p + 12.0f;              // P + K//2
  const float s = 0.77f;                  // |0.5| + 0.27
  float g[K_TAP]; float ssum = 0.f;
#pragma unroll
  for(int k=0;k<K_TAP;k++){ float z = ((float)k - c)/s; g[k] = expf(-0.5f*z*z); ssum += g[k]; }
  const float inv = 1.0f/(ssum + 1e-7f);
  // swizzled j position: XOR slot bits (3..4) with (o>>1)&3
  const int js = (j & ~24) | ((((j>>3) ^ (o>>1)) & 3) << 3);
#pragma unroll
  for(int k=0;k<K_TAP;k++){
    const int d = (K_TAP-1)-k;
    const float v  = w * (g[k]*inv);
    const unsigned short h1 = f2bf(v);
    const float r1 = v - bf2f(h1);
    const unsigned short h2 = f2bf(r1);
    const float r2 = r1 - bf2f(h2);
    const unsigned short h3 = f2bf(r2);
    const size_t idx = (size_t)(d*H_DIM + o)*J_DIM + js;
    kdh[idx] = h1; kdm[idx] = h2; kdl[idx] = h3;
  }
}

// ---------------------------------------------------------------------------
// 2) Delayed causal conv as MFMA GEMM.
//    y[r,o] = sum_d sum_j spk[r-64d, j]*(hi+mid+lo)[d,o,j], rows<0 -> 0.
//    128x64 block, 4 waves (2x2), wave tile 64x32, 16x16x32 bf16 MFMA,
//    double-buffered LDS (20KB/buf) -> 4 blocks/CU (160KB LDS exactly).
//    All LDS accesses slot-swizzled: phys_slot = logical_slot ^ ((row>>1)&3).
// ---------------------------------------------------------------------------
__global__ __launch_bounds__(256,4) void conv_mfma_k(const unsigned char* __restrict__ spk,
    const unsigned short* __restrict__ kdh, const unsigned short* __restrict__ kdm,
    const unsigned short* __restrict__ kdl, float* __restrict__ y){
  // per buf: A[128][32] @0 | H[64][32] @4096 | M @6144 | L @8192 (shorts)
  __shared__ unsigned short lds[2][10240];
  const int tid = threadIdx.x, lane = tid & 63, wave = tid >> 6;
  const int m0 = blockIdx.x * MB, n0 = blockIdx.y * NB;
  const int wm0 = (wave >> 1) << 6;   // 0 / 64
  const int wn0 = (wave & 1) << 5;    // 0 / 32

  const int arow = tid >> 1;          // A staging: row 0..127
  const int acol = (tid & 1) << 4;    // u8 col offset 0/16
  const int brow = tid >> 2;          // B staging: row 0..63
  const int boff = (tid & 3) << 3;    // element offset 0,8,16,24 (phys slot)

  // swizzled fragment-read slot offset (shorts): (logical slot lane>>4) ^ ((row>>1)&3)
  const int bslot = (((lane>>4) ^ (lane>>1)) & 3) << 3;

  f32x4 acc[4][2];
#pragma unroll
  for(int m=0;m<4;m++)
#pragma unroll
    for(int n=0;n<2;n++) acc[m][n] = (f32x4){0.f,0.f,0.f,0.f};

  unsigned areg[4];

#define LOAD_A(t) do{ \
    const int d_ = (t)>>3, jc_ = ((t)&7)<<5; \
    const int gr_ = m0 + arow - (d_<<6); \
    if(gr_ >= 0){ \
      const uint4 v_ = *(const uint4*)(spk + (size_t)gr_*J_DIM + jc_ + acol); \
      areg[0]=v_.x; areg[1]=v_.y; areg[2]=v_.z; areg[3]=v_.w; \
    } else { areg[0]=0u; areg[1]=0u; areg[2]=0u; areg[3]=0u; } \
  }while(0)

#define STAGE_B(buf,t) do{ \
    const int d_ = (t)>>3, jc_ = ((t)&7)<<5; \
    const size_t go_ = (size_t)(d_*H_DIM + n0 + brow)*J_DIM + jc_ + boff; \
    unsigned short* lb_ = &lds[buf][4096] + wave*512; \
    gl16(kdh + go_, lb_); \
    gl16(kdm + go_, lb_ + 2048); \
    gl16(kdl + go_, lb_ + 4096); \
  }while(0)

#define WRITE_A(buf) do{ \
    unsigned o_[8]; \
    _Pragma("unroll") \
    for(int q=0;q<4;q++){ \
      const unsigned w_ = areg[q]; \
      o_[2*q]   = ((w_ & 1u)         | ((w_ & 0x100u)      << 8)) * 0x3F80u; \
      o_[2*q+1] = (((w_ >> 16) & 1u) | ((w_ & 0x1000000u) >> 8)) * 0x3F80u; \
    } \
    const int mask_ = (arow>>1)&3; \
    const int s0_ = (tid&1)<<1; \
    unsigned* base_ = (unsigned*)&lds[buf][0] + arow*16; \
    *(uint4*)(base_ + (((s0_  )^mask_)<<2)) = (uint4){o_[0],o_[1],o_[2],o_[3]}; \
    *(uint4*)(base_ + (((s0_+1)^mask_)<<2)) = (uint4){o_[4],o_[5],o_[6],o_[7]}; \
  }while(0)

  // prologue: stage step 0 into buf 0
  LOAD_A(0);
  STAGE_B(0,0);
  WRITE_A(0);
  __syncthreads();

  int cur = 0;
  for(int t=0; t<NST; ++t){
    const int nxt = cur ^ 1;
    if(t+1 < NST){ LOAD_A(t+1); STAGE_B(nxt, t+1); }   // issue early (T14)
    const unsigned short* A  = &lds[cur][0];
    const unsigned short* Hh = &lds[cur][4096];
    const unsigned short* Mm = &lds[cur][6144];
    const unsigned short* Ll = &lds[cur][8192];
    bf16x8 af[4], hf[2], mf[2], lf[2];
#pragma unroll
    for(int m=0;m<4;m++)
      af[m] = *(const bf16x8*)(A + (wm0 + m*16 + (lane&15))*KS + bslot);
#pragma unroll
    for(int n=0;n<2;n++){
      const int ro = (wn0 + n*16 + (lane&15))*KS + bslot;
      hf[n] = *(const bf16x8*)(Hh + ro);
      mf[n] = *(const bf16x8*)(Mm + ro);
      lf[n] = *(const bf16x8*)(Ll + ro);
    }
#pragma unroll
    for(int m=0;m<4;m++)
#pragma unroll
      for(int n=0;n<2;n++){
        acc[m][n] = __builtin_amdgcn_mfma_f32_16x16x32_bf16(af[m], hf[n], acc[m][n], 0,0,0);
        acc[m][n] = __builtin_amdgcn_mfma_f32_16x16x32_bf16(af[m], mf[n], acc[m][n], 0,0,0);
        acc[m][n] = __builtin_amdgcn_mfma_f32_16x16x32_bf16(af[m], lf[n], acc[m][n], 0,0,0);
      }
    if(t+1 < NST) WRITE_A(nxt);   // write-late: areg arrived under the MFMAs
    __syncthreads();
    cur = nxt;
  }

  // epilogue: C/D mapping col=lane&15, row=(lane>>4)*4+r  [m89-verified]
  const int r0 = m0 + wm0 + ((lane>>4)<<2);
  const int c0 = n0 + wn0 + (lane&15);
#pragma unroll
  for(int m=0;m<4;m++)
#pragma unroll
    for(int n=0;n<2;n++)
#pragma unroll
      for(int r=0;r<4;r++)
        y[(size_t)(r0 + m*16 + r)*H_DIM + c0 + n*16] = acc[m][n][r];
#undef LOAD_A
#undef STAGE_B
#undef WRITE_A
}

// ---------------------------------------------------------------------------
// 3) BatchNorm training stats (two-stage, fp64 accumulators, fixed order)
// ---------------------------------------------------------------------------
__global__ void bn_stats_k(const float* __restrict__ y, double* __restrict__ part){
  const int o   = threadIdx.x;
  const int blk = blockIdx.x;         // 0..127
  const int rows = M_DIM / STATB;     // 256
  const float* p = y + (size_t)(blk*rows)*H_DIM + o;
  double s = 0.0, s2 = 0.0;
  for(int r=0;r<rows;r++){
    double v = (double)p[(size_t)r*H_DIM];
    s  += v;
    s2 += v*v;
  }
  part[blk*H_DIM + o]               = s;
  part[STATB*H_DIM + blk*H_DIM + o] = s2;
}

__global__ void bn_final_k(const double* __restrict__ part, float* __restrict__ sc,
                           float* __restrict__ sh, const float* __restrict__ gamma_,
                           const float* __restrict__ bb_, int layer){
  const int o = threadIdx.x;
  double s = 0.0, s2 = 0.0;
  for(int b=0;b<STATB;b++){
    s  += part[b*H_DIM + o];
    s2 += part[STATB*H_DIM + b*H_DIM + o];
  }
  const double inv_n = 1.0 / (double)M_DIM;
  const double m   = s * inv_n;
  const double var = s2 * inv_n - m*m;      // biased, like jnp.var
  const double rs  = 1.0 / sqrt(var + (double)1e-5f);
  const float g  = gamma_[layer*H_DIM + o];
  const float bv = bb_[layer*H_DIM + o];
  const float scale = (float)((double)g * rs);
  sc[o] = scale;
  sh[o] = (float)((double)bv - m*(double)scale);
}

// ---------------------------------------------------------------------------
// 4) LIF soft-reset scan. One thread per (b,h), 8-deep prefetch.
//    TOUT=u8 inter-layer spikes, f32 final output (in-place on d_out).
//    NOTE: no __restrict__ on yin/sout — they alias for the final layer.
// ---------------------------------------------------------------------------
template<typename TOUT>
__global__ void lif_k(const float* yin, TOUT* sout,
                      const float* __restrict__ sc_, const float* __restrict__ sh_,
                      const float* __restrict__ beta_, const float* __restrict__ U0_,
                      int layer){
  const int idx = blockIdx.x*64 + threadIdx.x;   // 0..16383 = b*256+h
  const int h = idx & (H_DIM-1);
  const float scale = sc_[h];
  const float shift = sh_[h];
  const float beta  = beta_[layer*H_DIM + h];
  const float ombeta = 1.0f - beta;
  float U = U0_[layer*NBH + idx];
  float S = 0.f;
  float cur[8];
#pragma unroll
  for(int i=0;i<8;i++) cur[i] = yin[(size_t)i*NBH + idx];
  for(int t=0;t<T_DIM;t+=8){
    float nx[8];
#pragma unroll
    for(int i=0;i<8;i++){
      const int tt = t + 8 + i;
      nx[i] = (tt < T_DIM) ? yin[(size_t)tt*NBH + idx] : 0.f;
    }
#pragma unroll
    for(int i=0;i<8;i++){
      const float yv = fmaf(cur[i], scale, shift);
      U = beta*(U - S) + ombeta*yv;
      S = (U > 1.0f) ? 1.f : 0.f;              // (U - THETA) > 0
      sout[(size_t)(t+i)*NBH + idx] = (TOUT)S;
    }
#pragma unroll
    for(int i=0;i<8;i++) cur[i] = nx[i];
  }
}

// ---------------------------------------------------------------------------
// Launch. ws layout (18.75 MB total):
//   spk  [0,          8,388,608)    32768*256 u8 spikes (layer input)
//   kdh  [8,388,608, 11,665,408)    25*256*256 bf16 (hi,  pre-swizzled)
//   kdm  [11,665,408,14,942,208)    25*256*256 bf16 (mid, pre-swizzled)
//   kdl  [14,942,208,18,219,008)    25*256*256 bf16 (lo,  pre-swizzled)
//   part [18,219,008,18,743,296)    2*128*256 f64 BN partials
//   sc   [18,743,296,+1024) f32 ; sh [18,744,320,+1024) f32
// Conv y always lands in d_out (fully rewritten each layer before any read).
// ---------------------------------------------------------------------------
extern "C" void kernel_launch(void* const* d_in, const int* in_sizes, int n_in,
                              void* d_out, int out_size, void* d_ws, size_t ws_size,
                              hipStream_t stream){
  const float* x    = (const float*)d_in[0];
  const float* W    = (const float*)d_in[1];
  const float* P    = (const float*)d_in[2];
  const float* beta = (const float*)d_in[3];
  const float* gam  = (const float*)d_in[4];
  const float* bb   = (const float*)d_in[5];
  const float* U0   = (const float*)d_in[6];
  float* out = (float*)d_out;

  char* ws = (char*)d_ws;
  unsigned char*  spk  = (unsigned char*)ws;
  unsigned short* kdh  = (unsigned short*)(ws + 8388608);
  unsigned short* kdm  = (unsigned short*)(ws + 11665408);
  unsigned short* kdl  = (unsigned short*)(ws + 14942208);
  double*         part = (double*)(ws + 18219008);
  float*          sc   = (float*)(ws + 18743296);
  float*          sh   = sc + 256;

  cast_u8_k<<<dim3((M_DIM*J_DIM)/1024), dim3(256), 0, stream>>>(x, spk);

  for(int l=0;l<NL;l++){
    build_kern_k<<<dim3(H_DIM), dim3(J_DIM), 0, stream>>>(W, P, kdh, kdm, kdl, l);
    conv_mfma_k<<<dim3(M_DIM/MB, H_DIM/NB), dim3(256), 0, stream>>>(spk, kdh, kdm, kdl, out);
    bn_stats_k<<<dim3(STATB), dim3(H_DIM), 0, stream>>>(out, part);
    bn_final_k<<<dim3(1), dim3(H_DIM), 0, stream>>>(part, sc, sh, gam, bb, l);
    if(l < NL-1) lif_k<unsigned char><<<dim3(NBH/64), dim3(64), 0, stream>>>(out, spk, sc, sh, beta, U0, l);
    else         lif_k<float>        <<<dim3(NBH/64), dim3(64), 0, stream>>>(out, out, sc, sh, beta, U0, l);
  }
}

// Round 6
// 676.711 us; speedup vs baseline: 1.5103x; 1.5103x over previous
//
#include <hip/hip_runtime.h>
#include <math.h>

// Model dims (fixed by the reference)
#define T_DIM 512
#define B_DIM 64
#define J_DIM 256
#define H_DIM 256
#define K_TAP 25
#define NL    3
#define M_DIM (T_DIM*B_DIM)   // 32768 rows = (t,b)
#define NBH   (B_DIM*H_DIM)   // 16384
#define STATB 128
#define GUARD_ROWS 1536                  // 64*24 zero rows before row 0
#define GUARD_BYTES (GUARD_ROWS*J_DIM)   // 393216

// conv GEMM tiling: 128(M) x 64(N) block, 4 waves (2x2), wave tile 64x32, BK=64
#define MB 128
#define NB 64
#define BK 64
#define NST (K_TAP*(J_DIM/BK))   // 100 K-steps

typedef __attribute__((ext_vector_type(4))) int   i32x4;

__device__ __forceinline__ void gl16(const void* g, void* l){ // async global->LDS, 16B/lane
  __builtin_amdgcn_global_load_lds((const __attribute__((address_space(1))) unsigned int*)g,
                                   (__attribute__((address_space(3))) unsigned int*)l, 16, 0, 0);
}

// ---------------------------------------------------------------------------
// 0a) zero the causal guard region (d_ws is poisoned, must zero every call)
// ---------------------------------------------------------------------------
__global__ void zero_guard_k(unsigned char* __restrict__ g){
  *(uint4*)(g + (size_t)(blockIdx.x*256 + threadIdx.x)*16) = (uint4){0,0,0,0};
}

// 0b) cast f32 binary input -> u8 spikes
__global__ void cast_u8_k(const float* __restrict__ x, unsigned char* __restrict__ s){
  const int i = blockIdx.x*256 + threadIdx.x;       // one float4 per thread
  const float4 v = *(const float4*)(x + (size_t)i*4);
  uchar4 o; o.x=(unsigned char)v.x; o.y=(unsigned char)v.y;
  o.z=(unsigned char)v.z; o.w=(unsigned char)v.w;
  *(uchar4*)(s + (size_t)i*4) = o;
}

// ---------------------------------------------------------------------------
// 1) DCLS gaussian kernel -> 23-bit fixed point, 3 signed-i8 digit planes.
//    kd[d][o][j] = W[o,j]*gnorm[o,j,k=24-d].  Per-column power-of-2 scale s_o
//    (maxv in (s_o/2, s_o]); q = rint(kd/s_o * 2^22) in [-2^22, 2^22];
//    q = b2*2^16 + b1*2^8 + b0 exactly, each digit in [-128,127] (|b2|<=65).
//    fsc[o] = s_o * 2^-22 (exact float, power of 2).
// ---------------------------------------------------------------------------
__global__ void build_kern_k(const float* __restrict__ W, const float* __restrict__ P,
                             signed char* __restrict__ k0, signed char* __restrict__ k1,
                             signed char* __restrict__ k2, float* __restrict__ fsc, int layer){
  __shared__ float red[256];
  const int o = blockIdx.x, j = threadIdx.x;
  const float w = W[(layer*H_DIM + o)*J_DIM + j];
  const float p = P[(layer*H_DIM + o)*J_DIM + j];
  const float c = p + 12.0f;              // P + K//2
  const float sg = 0.77f;                 // |0.5| + 0.27
  float v[K_TAP]; float ssum = 0.f;
#pragma unroll
  for(int k=0;k<K_TAP;k++){ float z = ((float)k - c)/sg; v[k] = expf(-0.5f*z*z); ssum += v[k]; }
  const float inv = 1.0f/(ssum + 1e-7f);
  float mv = 0.f;
#pragma unroll
  for(int k=0;k<K_TAP;k++){ v[k] = w * (v[k]*inv); mv = fmaxf(mv, fabsf(v[k])); }
  red[j] = mv; __syncthreads();
  for(int st=128; st; st>>=1){ if(j<st) red[j] = fmaxf(red[j], red[j+st]); __syncthreads(); }
  int e; frexpf(red[0], &e);              // maxv = f*2^e, f in [0.5,1)
  const float invq = ldexpf(1.f, 22 - e); // 2^22 / s_o
#pragma unroll
  for(int k=0;k<K_TAP;k++){
    const int d = (K_TAP-1)-k;
    int q = (int)lrintf(v[k]*invq);
    const int b0 = (int)(signed char)(q & 0xFF); q = (q - b0) >> 8;
    const int b1 = (int)(signed char)(q & 0xFF); q = (q - b1) >> 8;
    const size_t idx = (size_t)(d*H_DIM + o)*J_DIM + j;
    k0[idx] = (signed char)b0; k1[idx] = (signed char)b1; k2[idx] = (signed char)q;
  }
  if(j==0) fsc[o] = ldexpf(1.f, e - 22);
}

// ---------------------------------------------------------------------------
// 2) Delayed causal conv as EXACT i8 MFMA GEMM (3 digit planes, i32 acc).
//    y[r,o] = fsc[o] * sum_d sum_j spk[r-64d,j] * q[d,o,j]  (guard rows = 0)
//    128x64 block, 4 waves 2x2, wave tile 64x32, mfma_i32_16x16x64_i8, BK=64.
//    A (u8 spikes) AND B (i8 digits) both staged by global_load_lds; LDS
//    linear, conflict-free via per-lane SOURCE slot permutation (m173):
//    slot ^= (row>>1)&3, matching read slot ((lane>>4)^(lane>>1))&3.
// ---------------------------------------------------------------------------
__global__ __launch_bounds__(256,3) void conv_mfma_k(const unsigned char* __restrict__ spk,
    const signed char* __restrict__ k0, const signed char* __restrict__ k1,
    const signed char* __restrict__ k2, const float* __restrict__ fsc,
    float* __restrict__ y){
  // per buf: A[128][64]u8 @0 | B0[64][64] @8192 | B1 @12288 | B2 @16384
  __shared__ unsigned char lds[2][20480];
  const int tid = threadIdx.x, lane = tid & 63, wave = tid >> 6;
  const int m0 = blockIdx.x * MB, n0 = blockIdx.y * NB;
  const int wm0 = (wave >> 1) << 6;   // 0 / 64
  const int wn0 = (wave & 1) << 5;    // 0 / 32

  const int srow  = tid >> 2;                        // staging row 0..63
  const int sslot = ((tid & 3) ^ (srow >> 1)) & 3;   // swizzled source 16B slot
  const int rslot = ((((lane>>4) ^ (lane>>1)) & 3) << 4);  // read slot byte off

  i32x4 acc0[4][2], acc1[4][2], acc2[4][2];
#pragma unroll
  for(int m=0;m<4;m++)
#pragma unroll
    for(int n=0;n<2;n++){
      acc0[m][n] = (i32x4){0,0,0,0};
      acc1[m][n] = (i32x4){0,0,0,0};
      acc2[m][n] = (i32x4){0,0,0,0};
    }

#define STAGE(buf,t) do{ \
    const int d_ = (t)>>2, jc_ = ((t)&3)<<6; \
    const unsigned char* ab_ = spk + (size_t)(m0 - (d_<<6) + GUARD_ROWS)*J_DIM + jc_ + sslot*16; \
    gl16(ab_ + (size_t)srow*J_DIM,      &lds[buf][0]    + wave*1024); \
    gl16(ab_ + (size_t)(srow+64)*J_DIM, &lds[buf][4096] + wave*1024); \
    const size_t bo_ = (size_t)(d_*H_DIM + n0 + srow)*J_DIM + jc_ + sslot*16; \
    gl16(k0 + bo_, &lds[buf][8192]  + wave*1024); \
    gl16(k1 + bo_, &lds[buf][12288] + wave*1024); \
    gl16(k2 + bo_, &lds[buf][16384] + wave*1024); \
  }while(0)

  // prologue
  STAGE(0,0);
  __syncthreads();

  int cur = 0;
  for(int t=0; t<NST; ++t){
    const int nxt = cur ^ 1;
    if(t+1 < NST) STAGE(nxt, t+1);            // issue early (T14)
    const unsigned char* Ab = &lds[cur][0];
    const unsigned char* B0 = &lds[cur][8192];
    const unsigned char* B1 = &lds[cur][12288];
    const unsigned char* B2 = &lds[cur][16384];
    i32x4 af[4], b0f[2], b1f[2], b2f[2];
#pragma unroll
    for(int m=0;m<4;m++)
      af[m] = *(const i32x4*)(Ab + (wm0 + m*16 + (lane&15))*64 + rslot);
#pragma unroll
    for(int n=0;n<2;n++){
      const int ro = (wn0 + n*16 + (lane&15))*64 + rslot;
      b0f[n] = *(const i32x4*)(B0 + ro);
      b1f[n] = *(const i32x4*)(B1 + ro);
      b2f[n] = *(const i32x4*)(B2 + ro);
    }
#pragma unroll
    for(int m=0;m<4;m++)
#pragma unroll
      for(int n=0;n<2;n++){
        acc0[m][n] = __builtin_amdgcn_mfma_i32_16x16x64_i8(af[m], b0f[n], acc0[m][n], 0,0,0);
        acc1[m][n] = __builtin_amdgcn_mfma_i32_16x16x64_i8(af[m], b1f[n], acc1[m][n], 0,0,0);
        acc2[m][n] = __builtin_amdgcn_mfma_i32_16x16x64_i8(af[m], b2f[n], acc2[m][n], 0,0,0);
      }
    __syncthreads();
    cur = nxt;
  }

  // epilogue: C/D mapping col=lane&15, row=(lane>>4)*4+r [shape-determined,
  // dtype-independent — m121-128]. Exact int64 digit recombine, then one
  // float rounding via power-of-2 scale.
  const int r0 = m0 + wm0 + ((lane>>4)<<2);
  const int c0 = n0 + wn0 + (lane&15);
  const double f0 = (double)fsc[c0];
  const double f1 = (double)fsc[c0+16];
#pragma unroll
  for(int m=0;m<4;m++)
#pragma unroll
    for(int n=0;n<2;n++){
      const double fs = n ? f1 : f0;
#pragma unroll
      for(int r=0;r<4;r++){
        const long long cmb = ((long long)acc2[m][n][r] << 16)
                            + ((long long)acc1[m][n][r] << 8)
                            +  (long long)acc0[m][n][r];
        y[(size_t)(r0 + m*16 + r)*H_DIM + c0 + n*16] = (float)((double)cmb * fs);
      }
    }
#undef STAGE
}

// ---------------------------------------------------------------------------
// 3) BatchNorm training stats (two-stage, fp64 accumulators, fixed order)
// ---------------------------------------------------------------------------
__global__ void bn_stats_k(const float* __restrict__ y, double* __restrict__ part){
  const int o   = threadIdx.x;
  const int blk = blockIdx.x;         // 0..127
  const int rows = M_DIM / STATB;     // 256
  const float* p = y + (size_t)(blk*rows)*H_DIM + o;
  double s = 0.0, s2 = 0.0;
  for(int r=0;r<rows;r++){
    double v = (double)p[(size_t)r*H_DIM];
    s  += v;
    s2 += v*v;
  }
  part[blk*H_DIM + o]               = s;
  part[STATB*H_DIM + blk*H_DIM + o] = s2;
}

__global__ void bn_final_k(const double* __restrict__ part, float* __restrict__ sc,
                           float* __restrict__ sh, const float* __restrict__ gamma_,
                           const float* __restrict__ bb_, int layer){
  const int o = threadIdx.x;
  double s = 0.0, s2 = 0.0;
  for(int b=0;b<STATB;b++){
    s  += part[b*H_DIM + o];
    s2 += part[STATB*H_DIM + b*H_DIM + o];
  }
  const double inv_n = 1.0 / (double)M_DIM;
  const double m   = s * inv_n;
  const double var = s2 * inv_n - m*m;      // biased, like jnp.var
  const double rs  = 1.0 / sqrt(var + (double)1e-5f);
  const float g  = gamma_[layer*H_DIM + o];
  const float bv = bb_[layer*H_DIM + o];
  const float scale = (float)((double)g * rs);
  sc[o] = scale;
  sh[o] = (float)((double)bv - m*(double)scale);
}

// ---------------------------------------------------------------------------
// 4) LIF soft-reset scan. One thread per (b,h), 8-deep prefetch.
//    TOUT=u8 inter-layer spikes, f32 final output (in-place on d_out).
//    NOTE: no __restrict__ on yin/sout — they alias for the final layer.
// ---------------------------------------------------------------------------
template<typename TOUT>
__global__ void lif_k(const float* yin, TOUT* sout,
                      const float* __restrict__ sc_, const float* __restrict__ sh_,
                      const float* __restrict__ beta_, const float* __restrict__ U0_,
                      int layer){
  const int idx = blockIdx.x*64 + threadIdx.x;   // 0..16383 = b*256+h
  const int h = idx & (H_DIM-1);
  const float scale = sc_[h];
  const float shift = sh_[h];
  const float beta  = beta_[layer*H_DIM + h];
  const float ombeta = 1.0f - beta;
  float U = U0_[layer*NBH + idx];
  float S = 0.f;
  float cur[8];
#pragma unroll
  for(int i=0;i<8;i++) cur[i] = yin[(size_t)i*NBH + idx];
  for(int t=0;t<T_DIM;t+=8){
    float nx[8];
#pragma unroll
    for(int i=0;i<8;i++){
      const int tt = t + 8 + i;
      nx[i] = (tt < T_DIM) ? yin[(size_t)tt*NBH + idx] : 0.f;
    }
#pragma unroll
    for(int i=0;i<8;i++){
      const float yv = fmaf(cur[i], scale, shift);
      U = beta*(U - S) + ombeta*yv;
      S = (U > 1.0f) ? 1.f : 0.f;              // (U - THETA) > 0
      sout[(size_t)(t+i)*NBH + idx] = (TOUT)S;
    }
#pragma unroll
    for(int i=0;i<8;i++) cur[i] = nx[i];
  }
}

// ---------------------------------------------------------------------------
// Launch. ws layout (14.22 MB):
//   spk  [0,          8,781,824)    guard(393216 zeros) + 32768*256 u8 spikes
//   k0   [8,781,824, 10,420,224)    25*256*256 i8 digit 0 (2^0)
//   k1   [10,420,224,12,058,624)    25*256*256 i8 digit 1 (2^8)
//   k2   [12,058,624,13,697,024)    25*256*256 i8 digit 2 (2^16)
//   fsc  [13,697,024,+1024)         256 f32 per-column scale
//   part [13,698,048,14,222,336)    2*128*256 f64 BN partials
//   sc   [14,222,336,+1024) f32 ; sh [14,223,360,+1024) f32
// Conv y always lands in d_out (fully rewritten each layer before any read).
// ---------------------------------------------------------------------------
extern "C" void kernel_launch(void* const* d_in, const int* in_sizes, int n_in,
                              void* d_out, int out_size, void* d_ws, size_t ws_size,
                              hipStream_t stream){
  const float* x    = (const float*)d_in[0];
  const float* W    = (const float*)d_in[1];
  const float* P    = (const float*)d_in[2];
  const float* beta = (const float*)d_in[3];
  const float* gam  = (const float*)d_in[4];
  const float* bb   = (const float*)d_in[5];
  const float* U0   = (const float*)d_in[6];
  float* out = (float*)d_out;

  char* ws = (char*)d_ws;
  unsigned char* spk  = (unsigned char*)ws;                 // guarded base
  unsigned char* spkd = spk + GUARD_BYTES;                  // data region
  signed char*   k0   = (signed char*)(ws + 8781824);
  signed char*   k1   = (signed char*)(ws + 10420224);
  signed char*   k2   = (signed char*)(ws + 12058624);
  float*         fsc  = (float*)(ws + 13697024);
  double*        part = (double*)(ws + 13698048);
  float*         sc   = (float*)(ws + 14222336);
  float*         sh   = sc + 256;

  zero_guard_k<<<dim3(GUARD_BYTES/4096), dim3(256), 0, stream>>>(spk);
  cast_u8_k<<<dim3((M_DIM*J_DIM)/1024), dim3(256), 0, stream>>>(x, spkd);

  for(int l=0;l<NL;l++){
    build_kern_k<<<dim3(H_DIM), dim3(J_DIM), 0, stream>>>(W, P, k0, k1, k2, fsc, l);
    conv_mfma_k<<<dim3(M_DIM/MB, H_DIM/NB), dim3(256), 0, stream>>>(spk, k0, k1, k2, fsc, out);
    bn_stats_k<<<dim3(STATB), dim3(H_DIM), 0, stream>>>(out, part);
    bn_final_k<<<dim3(1), dim3(H_DIM), 0, stream>>>(part, sc, sh, gam, bb, l);
    if(l < NL-1) lif_k<unsigned char><<<dim3(NBH/64), dim3(64), 0, stream>>>(out, spkd, sc, sh, beta, U0, l);
    else         lif_k<float>        <<<dim3(NBH/64), dim3(64), 0, stream>>>(out, out, sc, sh, beta, U0, l);
  }
}